// Round 1
// baseline (136.694 us; speedup 1.0000x reference)
//
#include <hip/hip_runtime.h>
#include <hip/hip_bf16.h>

// RelativeAttention: out = softmax_j(mask((query@Wq)·(key@Wk)^T)) @ (key@Wv) @ Wu + bu
// B=4, T=1024, E=1024, H=8, D=128. All GEMMs via bf16 MFMA (f32 accum).

typedef __attribute__((ext_vector_type(8))) short bf16x8;   // 8 bf16 (4 VGPRs)
typedef __attribute__((ext_vector_type(4))) float f32x4;    // MFMA C/D frag

static constexpr int BB = 4;
static constexpr int TT = 1024;
static constexpr int EE = 1024;
static constexpr int HH = 8;
static constexpr int DD = 128;

// ---------- helpers ----------
static __device__ __forceinline__ unsigned short f2b(float x) {
  union { float f; unsigned int u; } c; c.f = x;
  unsigned int r = c.u + 0x7fffu + ((c.u >> 16) & 1u);   // RTN-even
  return (unsigned short)(r >> 16);
}

static __device__ __forceinline__ void gload_lds16(const void* g, void* l) {
  __builtin_amdgcn_global_load_lds(
      (const __attribute__((address_space(1))) unsigned int*)g,
      (__attribute__((address_space(3))) unsigned int*)l, 16, 0, 0);
}

// ---------- f32 -> bf16 convert for query & key ----------
__global__ __launch_bounds__(256) void cvt_kernel(
    const float* __restrict__ qf, const float* __restrict__ kf,
    unsigned short* __restrict__ qb, unsigned short* __restrict__ kb) {
  int i = blockIdx.x * 256 + threadIdx.x;   // each thread: 4 elements of each
  float4 a = ((const float4*)qf)[i];
  ushort4 oa; oa.x = f2b(a.x); oa.y = f2b(a.y); oa.z = f2b(a.z); oa.w = f2b(a.w);
  ((ushort4*)qb)[i] = oa;
  float4 b = ((const float4*)kf)[i];
  ushort4 ob; ob.x = f2b(b.x); ob.y = f2b(b.y); ob.z = f2b(b.z); ob.w = f2b(b.w);
  ((ushort4*)kb)[i] = ob;
}

// ---------- weight transpose-convert: W (K x N) f32 -> Wt (N x K) bf16 ----------
struct WT4 { const float* src[4]; unsigned short* dst[4]; };

__global__ __launch_bounds__(256) void wtrans_kernel(WT4 wt) {
  const float* src = wt.src[blockIdx.z];
  unsigned short* dst = wt.dst[blockIdx.z];
  __shared__ float tile[32][33];
  int n0 = blockIdx.x * 32, k0 = blockIdx.y * 32;
  int tx = threadIdx.x, ty = threadIdx.y;   // (32, 8)
#pragma unroll
  for (int i = 0; i < 4; ++i)
    tile[ty + i * 8][tx] = src[(size_t)(k0 + ty + i * 8) * EE + n0 + tx];
  __syncthreads();
#pragma unroll
  for (int i = 0; i < 4; ++i)
    dst[(size_t)(n0 + ty + i * 8) * EE + k0 + tx] = f2b(tile[tx][ty + i * 8]);
}

// ---------- V transpose: vp [b,kt, h*128+d] -> vt [b,h,d, kt] (bf16) ----------
__global__ __launch_bounds__(256) void vtrans_kernel(
    const unsigned short* __restrict__ vp, unsigned short* __restrict__ vt) {
  int bh = blockIdx.z; int b = bh >> 3, h = bh & 7;
  int d0 = blockIdx.x * 32, kt0 = blockIdx.y * 32;
  __shared__ unsigned short tile[32][33];
  int tx = threadIdx.x, ty = threadIdx.y;
#pragma unroll
  for (int i = 0; i < 4; ++i)
    tile[ty + i * 8][tx] =
        vp[(size_t)(b * TT + kt0 + ty + i * 8) * EE + h * DD + d0 + tx];
  __syncthreads();
#pragma unroll
  for (int i = 0; i < 4; ++i)
    vt[(size_t)((b * HH + h) * DD + d0 + ty + i * 8) * TT + kt0 + tx] =
        tile[tx][ty + i * 8];
}

// ---------- GEMM core: C[M,N] = A[M,K] @ Bt[N,K]^T  (m97 structure) ----------
// 128x128 tile, BK=32, 4 waves (2x2), 4x4 16x16 fragments per wave.
static __device__ __forceinline__ void gemm_core(
    const unsigned short* __restrict__ A, const unsigned short* __restrict__ Bt,
    unsigned short* __restrict__ Cb, float* __restrict__ Cf,
    const float* __restrict__ bias) {
  constexpr int K = EE, N = EE;
  __shared__ __align__(16) unsigned short As[128 * 32];
  __shared__ __align__(16) unsigned short Bs[128 * 32];
  const int tid = threadIdx.x, lane = tid & 63, w = tid >> 6;
  const int wm = w >> 1, wn = w & 1;
  const int bm = blockIdx.x, bn = blockIdx.y;
  const int g4 = lane >> 4, l15 = lane & 15;
  const int srow = lane >> 2;            // 0..15 (row within 16-row chunk)
  const int scol = (lane & 3) * 8;       // bf16 elems within 64B row

  f32x4 acc[4][4] = {};

  for (int kt = 0; kt < K / 32; ++kt) {
    const int k0 = kt * 32;
#pragma unroll
    for (int it = 0; it < 2; ++it) {
      int r = it * 64 + w * 16;
      gload_lds16(A + (size_t)(bm * 128 + r + srow) * K + k0 + scol, As + r * 32);
      gload_lds16(Bt + (size_t)(bn * 128 + r + srow) * K + k0 + scol, Bs + r * 32);
    }
    __syncthreads();
    bf16x8 af[4], bf[4];
#pragma unroll
    for (int i = 0; i < 4; ++i) {
      af[i] = *(const bf16x8*)(As + (wm * 64 + i * 16 + l15) * 32 + g4 * 8);
      bf[i] = *(const bf16x8*)(Bs + (wn * 64 + i * 16 + l15) * 32 + g4 * 8);
    }
#pragma unroll
    for (int i = 0; i < 4; ++i)
#pragma unroll
      for (int j = 0; j < 4; ++j)
        acc[i][j] = __builtin_amdgcn_mfma_f32_16x16x32_bf16(af[i], bf[j],
                                                            acc[i][j], 0, 0, 0);
    __syncthreads();
  }

  // epilogue: C/D layout col=lane&15, row=(lane>>4)*4+reg
  const int rr = g4 * 4;
#pragma unroll
  for (int i = 0; i < 4; ++i) {
#pragma unroll
    for (int j = 0; j < 4; ++j) {
      int row = bm * 128 + wm * 64 + i * 16 + rr;
      int col = bn * 128 + wn * 64 + j * 16 + l15;
#pragma unroll
      for (int r = 0; r < 4; ++r) {
        float v = acc[i][j][r];
        if (Cf != nullptr)
          Cf[(size_t)(row + r) * N + col] = v + bias[col];
        else
          Cb[(size_t)(row + r) * N + col] = f2b(v);
      }
    }
  }
}

struct Gemm3 { const unsigned short* A[3]; const unsigned short* Bt[3];
               unsigned short* C[3]; };

__global__ __launch_bounds__(256) void proj_gemm_kernel(Gemm3 g) {
  int z = blockIdx.z;
  gemm_core(g.A[z], g.Bt[z], g.C[z], nullptr, nullptr);
}

__global__ __launch_bounds__(256) void out_gemm_kernel(
    const unsigned short* __restrict__ A, const unsigned short* __restrict__ Bt,
    float* __restrict__ Cf, const float* __restrict__ bias) {
  gemm_core(A, Bt, nullptr, Cf, bias);
}

// ---------- fused attention: per (q-tile of 64, head, batch) ----------
// 4 waves; wave owns 16 q-rows. KVBLK=64. Online softmax, mask -> -1e9.
__global__ __launch_bounds__(256) void attn_kernel(
    const unsigned short* __restrict__ q, const unsigned short* __restrict__ k,
    const unsigned short* __restrict__ vt, const int* __restrict__ mask,
    unsigned short* __restrict__ av) {
  __shared__ __align__(16) unsigned short Ks[64 * 128];   // swizzled
  __shared__ __align__(16) unsigned short Vs[128 * 64];   // swizzled (V^T tile)
  __shared__ __align__(16) unsigned short Ps[4][16][72];  // per-wave P strip

  const int tid = threadIdx.x, lane = tid & 63, w = tid >> 6;
  const int qt = blockIdx.x, h = blockIdx.y, b = blockIdx.z;
  const int i0 = qt * 64 + w * 16;
  const int g4 = lane >> 4, l15 = lane & 15;

  // hoist Q fragments (A-operand layout: row=lane&15, k=(lane>>4)*8+j)
  bf16x8 aq[4];
  {
    const unsigned short* qb =
        q + (size_t)(b * TT + i0 + l15) * EE + h * DD + g4 * 8;
#pragma unroll
    for (int kc = 0; kc < 4; ++kc) aq[kc] = *(const bf16x8*)(qb + kc * 32);
  }

  f32x4 oacc[8] = {};
  float mrun[4], lrun[4];
#pragma unroll
  for (int r = 0; r < 4; ++r) { mrun[r] = -__builtin_inff(); lrun[r] = 0.f; }

  for (int t = 0; t < 16; ++t) {
    // ---- stage K tile [64][128] (row-swizzled) ----
    {
      const unsigned short* kb = k + (size_t)(b * TT + t * 64) * EE + h * DD;
#pragma unroll
      for (int p = 0; p < 4; ++p) {
        int idx = p * 256 + tid;
        int row = idx >> 4, c16 = idx & 15;    // 16B chunks per 256B row
        float4 val = *(const float4*)(kb + (size_t)row * EE + c16 * 8);
        int addr = (row * 256 + c16 * 16) ^ ((row & 7) << 4);
        *(float4*)((char*)Ks + addr) = val;
      }
      const unsigned short* vb =
          vt + (size_t)((b * HH + h) * DD) * TT + t * 64;
#pragma unroll
      for (int p = 0; p < 4; ++p) {
        int idx = p * 256 + tid;
        int row = idx >> 3, c16 = idx & 7;     // 8 x 16B chunks per 128B row
        float4 val = *(const float4*)(vb + (size_t)row * TT + c16 * 8);
        int addr = (row * 128 + c16 * 16) ^ ((row & 7) << 4);
        *(float4*)((char*)Vs + addr) = val;
      }
    }
    __syncthreads();

    // ---- S = Q K^T (16 x 64 per wave) ----
    f32x4 sacc[4];
#pragma unroll
    for (int nt = 0; nt < 4; ++nt) {
      f32x4 s = {};
#pragma unroll
      for (int kc = 0; kc < 4; ++kc) {
        int krow = nt * 16 + l15;
        int addr = (krow * 256 + (kc * 32 + g4 * 8) * 2) ^ ((krow & 7) << 4);
        bf16x8 bk = *(const bf16x8*)((const char*)Ks + addr);
        s = __builtin_amdgcn_mfma_f32_16x16x32_bf16(aq[kc], bk, s, 0, 0, 0);
      }
      sacc[nt] = s;
    }

    // ---- mask (mask==0 -> -1e9, matching reference exactly) ----
    const int* mrow = mask + (size_t)(b * TT + i0 + g4 * 4) * TT + t * 64 + l15;
#pragma unroll
    for (int r = 0; r < 4; ++r)
#pragma unroll
      for (int nt = 0; nt < 4; ++nt)
        if (mrow[(size_t)r * TT + nt * 16] == 0) sacc[nt][r] = -1e9f;

    // ---- online softmax (per q-row; row lives across 16 lanes) ----
    float scale[4];
#pragma unroll
    for (int r = 0; r < 4; ++r) {
      float mx = fmaxf(fmaxf(sacc[0][r], sacc[1][r]),
                       fmaxf(sacc[2][r], sacc[3][r]));
#pragma unroll
      for (int d = 1; d < 16; d <<= 1) mx = fmaxf(mx, __shfl_xor(mx, d, 64));
      float mnew = fmaxf(mrun[r], mx);
      scale[r] = __expf(mrun[r] - mnew);   // -inf on first tile -> 0
      float s0 = 0.f;
#pragma unroll
      for (int nt = 0; nt < 4; ++nt) {
        float pv = __expf(sacc[nt][r] - mnew);
        Ps[w][g4 * 4 + r][nt * 16 + l15] = f2b(pv);
        s0 += pv;
      }
#pragma unroll
      for (int d = 1; d < 16; d <<= 1) s0 += __shfl_xor(s0, d, 64);
      lrun[r] = lrun[r] * scale[r] + s0;
      mrun[r] = mnew;
    }
#pragma unroll
    for (int dt = 0; dt < 8; ++dt)
#pragma unroll
      for (int r = 0; r < 4; ++r) oacc[dt][r] *= scale[r];

    // ---- PV: O += P (16x64) @ V (64x128) ---- (Ps is per-wave: no barrier)
#pragma unroll
    for (int kc2 = 0; kc2 < 2; ++kc2) {
      bf16x8 pa = *(const bf16x8*)(&Ps[w][l15][kc2 * 32 + g4 * 8]);
#pragma unroll
      for (int dt = 0; dt < 8; ++dt) {
        int vrow = dt * 16 + l15;
        int addr = (vrow * 128 + (kc2 * 32 + g4 * 8) * 2) ^ ((vrow & 7) << 4);
        bf16x8 bv = *(const bf16x8*)((const char*)Vs + addr);
        oacc[dt] = __builtin_amdgcn_mfma_f32_16x16x32_bf16(pa, bv, oacc[dt],
                                                           0, 0, 0);
      }
    }
    __syncthreads();   // protect Ks/Vs before next tile's staging
  }

  // ---- epilogue: att_vec = O / l ----
  float inv[4];
#pragma unroll
  for (int r = 0; r < 4; ++r) inv[r] = 1.f / lrun[r];
  unsigned short* ob =
      av + (size_t)(b * TT + i0 + g4 * 4) * EE + h * DD + l15;
#pragma unroll
  for (int dt = 0; dt < 8; ++dt)
#pragma unroll
    for (int r = 0; r < 4; ++r)
      ob[(size_t)r * EE + dt * 16] = f2b(oacc[dt][r] * inv[r]);
}

// ---------- launch ----------
extern "C" void kernel_launch(void* const* d_in, const int* in_sizes, int n_in,
                              void* d_out, int out_size, void* d_ws,
                              size_t ws_size, hipStream_t stream) {
  const float* query = (const float*)d_in[0];
  const float* key   = (const float*)d_in[1];
  const int*   mask  = (const int*)d_in[2];
  const float* Wq    = (const float*)d_in[3];
  const float* Wk    = (const float*)d_in[4];
  const float* Wv    = (const float*)d_in[5];
  const float* Wu    = (const float*)d_in[6];
  const float* bu    = (const float*)d_in[7];
  float* out = (float*)d_out;

  char* ws = (char*)d_ws;
  const size_t MB = 1024 * 1024;
  unsigned short* qbf = (unsigned short*)(ws);             // 8MB bf16 query
  unsigned short* kbf = (unsigned short*)(ws + 8 * MB);    // 8MB bf16 key
  unsigned short* Wqt = (unsigned short*)(ws + 16 * MB);   // 2MB each, N x K
  unsigned short* Wkt = (unsigned short*)(ws + 18 * MB);
  unsigned short* Wvt = (unsigned short*)(ws + 20 * MB);
  unsigned short* Wut = (unsigned short*)(ws + 22 * MB);
  unsigned short* qp  = (unsigned short*)(ws + 24 * MB);   // q proj
  unsigned short* kp  = (unsigned short*)(ws + 32 * MB);   // k proj
  unsigned short* vp  = (unsigned short*)(ws + 40 * MB);   // v proj
  unsigned short* vtb = (unsigned short*)(ws + 48 * MB);   // v transposed
  unsigned short* av  = (unsigned short*)(ws + 56 * MB);   // attention out

  cvt_kernel<<<4096, 256, 0, stream>>>(query, key, qbf, kbf);

  WT4 wt; wt.src[0] = Wq; wt.src[1] = Wk; wt.src[2] = Wv; wt.src[3] = Wu;
  wt.dst[0] = Wqt; wt.dst[1] = Wkt; wt.dst[2] = Wvt; wt.dst[3] = Wut;
  wtrans_kernel<<<dim3(32, 32, 4), dim3(32, 8), 0, stream>>>(wt);

  Gemm3 g3;
  g3.A[0] = qbf; g3.A[1] = kbf; g3.A[2] = kbf;
  g3.Bt[0] = Wqt; g3.Bt[1] = Wkt; g3.Bt[2] = Wvt;
  g3.C[0] = qp; g3.C[1] = kp; g3.C[2] = vp;
  proj_gemm_kernel<<<dim3(32, 8, 3), 256, 0, stream>>>(g3);

  vtrans_kernel<<<dim3(4, 32, 32), dim3(32, 8), 0, stream>>>(vp, vtb);

  attn_kernel<<<dim3(16, 8, 4), 256, 0, stream>>>(qp, kp, vtb, mask, av);

  out_gemm_kernel<<<dim3(32, 8), 256, 0, stream>>>(av, Wut, out, bu);
}